// Round 1
// baseline (733.315 us; speedup 1.0000x reference)
//
#include <hip/hip_runtime.h>
#include <cstdint>
#include <cstddef>

typedef _Float16 half8 __attribute__((ext_vector_type(8)));
typedef __fp16 fp16x2 __attribute__((ext_vector_type(2)));
typedef float f32x16 __attribute__((ext_vector_type(16)));
typedef float f32x2 __attribute__((ext_vector_type(2)));

// ---------------- hf8 decode (scalar, f32) ----------------
// code: sign(1) | e(4, bias 7) | m(3). e==0 -> m * 2^-9 ; else (1+m/8)*2^(e-7).
// Bit-identical to OCP e4m3fn except 0x7F/0xFF (|x|=480 vs NaN) — unreachable
// for this problem's data (|w| <= ~0.16).
__device__ __forceinline__ float dec_hf8(unsigned c) {
    unsigned e = (c >> 3) & 0xFu;
    unsigned m = c & 7u;
    float normal = __uint_as_float(((e + 120u) << 23) | (m << 20));
    float sub = (float)m * 0x1p-9f;
    float mag = (e != 0u) ? normal : sub;
    return (c & 0x80u) ? -mag : mag;
}

// decode 8 e4m3 codes (two packed words) -> 8 fp16, exact
__device__ __forceinline__ half8 dec8(unsigned w0, unsigned w1) {
#if __has_builtin(__builtin_amdgcn_cvt_pk_f32_fp8) && __has_builtin(__builtin_amdgcn_cvt_pkrtz)
    f32x2 a0 = __builtin_amdgcn_cvt_pk_f32_fp8((int)w0, false);
    f32x2 a1 = __builtin_amdgcn_cvt_pk_f32_fp8((int)w0, true);
    f32x2 a2 = __builtin_amdgcn_cvt_pk_f32_fp8((int)w1, false);
    f32x2 a3 = __builtin_amdgcn_cvt_pk_f32_fp8((int)w1, true);
    fp16x2 h0 = __builtin_amdgcn_cvt_pkrtz(a0.x, a0.y);  // exact: e4m3 subset of f16
    fp16x2 h1 = __builtin_amdgcn_cvt_pkrtz(a1.x, a1.y);
    fp16x2 h2 = __builtin_amdgcn_cvt_pkrtz(a2.x, a2.y);
    fp16x2 h3 = __builtin_amdgcn_cvt_pkrtz(a3.x, a3.y);
    half8 r = {(_Float16)h0.x, (_Float16)h0.y, (_Float16)h1.x, (_Float16)h1.y,
               (_Float16)h2.x, (_Float16)h2.y, (_Float16)h3.x, (_Float16)h3.y};
    return r;
#else
    half8 r;
#pragma unroll
    for (int i = 0; i < 4; ++i) r[i] = (_Float16)dec_hf8((w0 >> (8 * i)) & 0xFFu);
#pragma unroll
    for (int i = 0; i < 4; ++i) r[4 + i] = (_Float16)dec_hf8((w1 >> (8 * i)) & 0xFFu);
    return r;
#endif
}

// ---------------- prep A (new path): decode W codes int32 -> fp16 ----------------
__global__ __launch_bounds__(256) void decode_w(const int* __restrict__ codes,
                                                _Float16* __restrict__ out,
                                                long long n16) {
    long long i = (long long)blockIdx.x * 256 + threadIdx.x;
    if (i >= n16) return;
    long long base = i * 16;
    unsigned w[4];
#pragma unroll
    for (int q = 0; q < 4; ++q) {
        int4 c = *(const int4*)(codes + base + q * 4);
        w[q] = ((unsigned)c.x & 255u) | (((unsigned)c.y & 255u) << 8) |
               (((unsigned)c.z & 255u) << 16) | (((unsigned)c.w & 255u) << 24);
    }
    *(half8*)(out + base) = dec8(w[0], w[1]);
    *(half8*)(out + base + 8) = dec8(w[2], w[3]);
}

// ---------------- prep (old path): repack weight codes int32 -> uint8 ----------------
__global__ __launch_bounds__(256) void repack_codes(const int* __restrict__ codes,
                                                    unsigned* __restrict__ out,
                                                    long long n16) {
    long long i = (long long)blockIdx.x * 256 + threadIdx.x;
    if (i >= n16) return;
    long long base = i * 16;
    unsigned w[4];
#pragma unroll
    for (int q = 0; q < 4; ++q) {
        int4 c = *(const int4*)(codes + base + q * 4);
        w[q] = ((unsigned)c.x & 255u) | (((unsigned)c.y & 255u) << 8) |
               (((unsigned)c.z & 255u) << 16) | (((unsigned)c.w & 255u) << 24);
    }
    *(uint4*)(out + i * 4) = make_uint4(w[0], w[1], w[2], w[3]);
}

// ---------------- prep: X fp32 -> fp16 ----------------
__global__ __launch_bounds__(256) void cvt_x(const float* __restrict__ X,
                                             _Float16* __restrict__ out,
                                             long long n8) {
    long long i = (long long)blockIdx.x * 256 + threadIdx.x;
    if (i >= n8) return;
    long long base = i * 8;
    float4 v0 = *(const float4*)(X + base);
    float4 v1 = *(const float4*)(X + base + 4);
    half8 h = {(_Float16)v0.x, (_Float16)v0.y, (_Float16)v0.z, (_Float16)v0.w,
               (_Float16)v1.x, (_Float16)v1.y, (_Float16)v1.z, (_Float16)v1.w};
    *(half8*)(out + base) = h;
}

// ---------------- async global->LDS (16B/lane, wave-uniform LDS base) ----------------
__device__ __forceinline__ void gl_lds16(const void* g, void* l) {
    __builtin_amdgcn_global_load_lds(
        (__attribute__((address_space(1))) void*)(g),
        (__attribute__((address_space(3))) void*)(l), 16, 0, 0);
}

// per-row LDS XOR key (verified conflict-free + correct in previous rounds)
#define FKEY(r) (((r) ^ ((r) >> 3)) & 7)

// raw barrier (no vmcnt/lgkm drain) + compiler memory fence both sides
#define BAR()                                  \
    {                                          \
        asm volatile("" ::: "memory");         \
        __builtin_amdgcn_s_barrier();          \
        asm volatile("" ::: "memory");         \
    }

// ================= 8-phase 256x256 GEMM: C = Xh[M][K] * Wh[N][K]^T + bias =========
// BK=64, 8 waves (2m x 4n), wave tile 128x64 as 4x2 of 32x32x16 f16 MFMA.
// LDS 128KB: A/B each [2 dbuf][2 half][128 rows][64 f16], FKEY-swizzled chunks.
// Phase (MH,NH) computes block-quadrant MH*128 rows x NH*128 cols over full BK;
// reads ONLY A-half MH + B-half NH -> halves free progressively:
//   A0 last read Q1 -> restaged (t+2) at Q2 ; B0 last read Q2 -> restaged at Q3 ;
//   A1,B1 last read Q3 -> restaged (t+1... next occupant) at Q0/Q1 of next block.
// Counted vmcnt(4) once per K-tile boundary (2 halves x 2 loads in flight);
// vmcnt(0) only entering the final tile. setprio(1) around MFMA cluster (T5).
__global__ __launch_bounds__(512) void hgemm_8ph(const _Float16* __restrict__ Xh,
                                                 const _Float16* __restrict__ Wh,
                                                 const int* __restrict__ bias_codes,
                                                 float* __restrict__ C,
                                                 int M, int N, int K) {
    __shared__ _Float16 As[2][2][128 * 64];
    __shared__ _Float16 Bs[2][2][128 * 64];

    const int tid  = threadIdx.x;
    const int lane = tid & 63;
    const int wid  = tid >> 6;

    const int nT = N >> 8;
    const int mT = M >> 8;
    int mTile, nTile;
    int bid = blockIdx.x;
    if (mT == 16) {                  // XCD map: XCD x owns m-band {2x,2x+1} x all n
        int x = bid & 7;             // bid%8 == XCD round-robin heuristic
        int l = bid >> 3;            // 0 .. 2*nT-1
        mTile = (x << 1) + (l & 1);  // 2 m-tiles share each XCD's 4MB L2 X-band
        nTile = l >> 1;              // consecutive bids share the W panel
    } else {
        mTile = bid / nT;
        nTile = bid % nT;
    }
    const int mB = mTile << 8;
    const int nB = nTile << 8;
    const int kIters = K >> 6;

    // ---- staging source geometry: thread stages rows srow and srow+64 of a half
    const int    srow = tid >> 3;                       // 0..63
    const int    sg   = (tid & 7) ^ FKEY(srow);         // swizzled source chunk
    const size_t soff = (size_t)srow * K + ((size_t)sg << 3);
    const size_t rowStep = (size_t)K << 6;              // +64 rows (FKEY(r+64)==FKEY(r))
    const _Float16* aS0 = Xh + (size_t)mB * K + soff;
    const _Float16* aS1 = Xh + (size_t)(mB + 128) * K + soff;
    const _Float16* bS0 = Wh + (size_t)nB * K + soff;
    const _Float16* bS1 = Wh + (size_t)(nB + 128) * K + soff;

#define STG(SRC, DSTARR, tt, half_)                                   \
    {                                                                 \
        char* d_ = (char*)(&DSTARR[(tt) & 1][half_][0]);              \
        const _Float16* s_ = (SRC) + ((size_t)(tt) << 6);             \
        gl_lds16(s_, d_ + (tid << 4));                                \
        gl_lds16(s_ + rowStep, d_ + ((512 + tid) << 4));              \
    }

    // ---- fragment geometry (identical to verified round-5 pattern)
    const int wm   = wid >> 2;                 // 0..1
    const int wn   = wid & 3;                  // 0..3
    const int fr   = lane & 31;
    const int kh   = lane >> 5;
    const int fkey = FKEY(fr);
    const int lrA0 = (wm << 6) + fr;           // local A row (half-relative), +32 for i=1
    const int lrB  = (wn << 5) + fr;           // local B row (half-relative)
    const int keyB = fkey ^ ((wn & 1) << 2);

    f32x16 acc[2][2][2] = {};  // [MH][i][NH], all indices compile-time in unrolled code

#define PHASE(MH, NH, STAGE_STMT, TAIL_STMT)                                          \
    {                                                                                 \
        const _Float16* Ab = &As[buf][MH][0];                                         \
        const _Float16* Bb = &Bs[buf][NH][0];                                         \
        half8 a0[4], a1[4], bb[4];                                                    \
        _Pragma("unroll") for (int ks = 0; ks < 4; ++ks) {                            \
            const int lc = (ks << 1) + kh;                                            \
            a0[ks] = *(const half8*)(Ab + (lrA0 << 6) + ((lc ^ fkey) << 3));          \
            a1[ks] = *(const half8*)(Ab + ((lrA0 + 32) << 6) + ((lc ^ fkey ^ 4) << 3)); \
            bb[ks] = *(const half8*)(Bb + (lrB << 6) + ((lc ^ keyB) << 3));           \
        }                                                                             \
        STAGE_STMT;                                                                   \
        BAR();                                                                        \
        __builtin_amdgcn_s_setprio(1);                                                \
        _Pragma("unroll") for (int ks = 0; ks < 4; ++ks) {                            \
            acc[MH][0][NH] = __builtin_amdgcn_mfma_f32_32x32x16_f16(                  \
                a0[ks], bb[ks], acc[MH][0][NH], 0, 0, 0);                             \
            acc[MH][1][NH] = __builtin_amdgcn_mfma_f32_32x32x16_f16(                  \
                a1[ks], bb[ks], acc[MH][1][NH], 0, 0, 0);                             \
        }                                                                             \
        __builtin_amdgcn_s_setprio(0);                                                \
        TAIL_STMT;                                                                    \
        BAR();                                                                        \
    }

    // ---- prologue: issue 6 halves in steady-state order, then counted wait
    STG(aS0, As, 0, 0);
    STG(bS0, Bs, 0, 0);
    STG(aS1, As, 0, 1);
    STG(bS1, Bs, 0, 1);
    if (kIters > 1) {
        STG(aS0, As, 1, 0);
        STG(bS0, Bs, 1, 0);
        asm volatile("s_waitcnt vmcnt(4)" ::: "memory");  // tile0 landed; A0/B0(1) in flight
    } else {
        asm volatile("s_waitcnt vmcnt(0)" ::: "memory");
    }
    BAR();

    for (int t = 0; t < kIters; ++t) {
        const int buf = t & 1;
        PHASE(0, 0, { if (t + 1 < kIters) STG(aS1, As, t + 1, 1); }, {});
        PHASE(0, 1, { if (t + 1 < kIters) STG(bS1, Bs, t + 1, 1); }, {});
        PHASE(1, 0, { if (t + 2 < kIters) STG(aS0, As, t + 2, 0); }, {});
        PHASE(1, 1, { if (t + 2 < kIters) STG(bS0, Bs, t + 2, 0); },
              {
                  if (t + 2 < kIters) {
                      asm volatile("s_waitcnt vmcnt(4)" ::: "memory");  // steady boundary
                  } else if (t + 1 < kIters) {
                      asm volatile("s_waitcnt vmcnt(0)" ::: "memory");  // entering last tile
                  }
              });
    }

#undef PHASE
#undef STG

    // ---- epilogue: col = lane&31, row = (reg&3) + 8*(reg>>2) + 4*(lane>>5) [m74/m101]
#pragma unroll
    for (int NH = 0; NH < 2; ++NH) {
        const int col = nB + (NH << 7) + (wn << 5) + fr;
        const float bv = dec_hf8((unsigned)bias_codes[col]);
#pragma unroll
        for (int MH = 0; MH < 2; ++MH)
#pragma unroll
            for (int i = 0; i < 2; ++i) {
                const int rbase = mB + (MH << 7) + (wm << 6) + (i << 5) + (kh << 2);
#pragma unroll
                for (int r = 0; r < 16; ++r) {
                    const int row = rbase + (r & 3) + ((r >> 2) << 3);
                    C[(size_t)row * N + col] = acc[MH][i][NH][r] + bv;
                }
            }
    }
}

// ================= fallback GEMM (previous verified kernel, 128x256 tile) =========
__global__ __launch_bounds__(512) void hgemm_x2(const _Float16* __restrict__ Xh,
                                                const unsigned char* __restrict__ W8,
                                                const int* __restrict__ bias_codes,
                                                float* __restrict__ C,
                                                int M, int N, int K) {
    __shared__ _Float16 As[128 * 64];
    __shared__ _Float16 Bs[256 * 64];

    const int tid  = threadIdx.x;
    const int lane = tid & 63;
    const int wid  = tid >> 6;

    const int nT = N >> 8;
    const int mT = M >> 7;
    int mTile, nTile;
    int bid = blockIdx.x;
    if (mT == 32) {
        int x = bid & 7;
        int l = bid >> 3;
        mTile = (x << 2) + (l & 3);
        nTile = l >> 2;
    } else {
        mTile = bid / nT;
        nTile = bid % nT;
    }
    const int mB = mTile << 7;
    const int nB = nTile << 8;

    const int kIters = K >> 6;

    const _Float16* aptr[2];
#pragma unroll
    for (int it = 0; it < 2; ++it) {
        int p = it * 512 + tid;
        int row = p >> 3;
        int g = (p & 7) ^ FKEY(row);
        aptr[it] = Xh + (size_t)(mB + row) * K + (g << 3);
    }
    char* as_base = (char*)As;

    const int brow = tid >> 1;
    const int bhc  = tid & 1;
    const unsigned char* bptr = W8 + (size_t)(nB + brow) * K + (bhc << 5);
    const int bfk = FKEY(brow);
    _Float16* brow_lds = Bs + (brow << 6);
    const int bg0 = bhc << 2;

    const int wm = (wid >> 2) << 6;
    const int wn = (wid & 3) << 6;
    const int fr = lane & 31;
    const int kh = lane >> 5;
    const int fkey = FKEY(fr);

    f32x16 acc[2][2] = {};

    for (int kt = 0; kt < kIters; ++kt) {
#pragma unroll
        for (int it = 0; it < 2; ++it) {
            gl_lds16(aptr[it], as_base + ((it * 512 + tid) << 4));
            aptr[it] += 64;
        }
        uint4 q0 = *(const uint4*)(bptr);
        uint4 q1 = *(const uint4*)(bptr + 16);
        bptr += 64;
        half8 d0 = dec8(q0.x, q0.y);
        half8 d1 = dec8(q0.z, q0.w);
        half8 d2 = dec8(q1.x, q1.y);
        half8 d3 = dec8(q1.z, q1.w);
        *(half8*)(brow_lds + (((bg0 + 0) ^ bfk) << 3)) = d0;
        *(half8*)(brow_lds + (((bg0 + 1) ^ bfk) << 3)) = d1;
        *(half8*)(brow_lds + (((bg0 + 2) ^ bfk) << 3)) = d2;
        *(half8*)(brow_lds + (((bg0 + 3) ^ bfk) << 3)) = d3;
        __syncthreads();

#pragma unroll
        for (int ks = 0; ks < 4; ++ks) {
            const int lc = (ks << 1) + kh;
            half8 a[2], bb[2];
#pragma unroll
            for (int i = 0; i < 2; ++i) {
                const int co = ((lc ^ fkey ^ (i << 2)) << 3);
                a[i]  = *(const half8*)(As + ((wm + (i << 5) + fr) << 6) + co);
                bb[i] = *(const half8*)(Bs + ((wn + (i << 5) + fr) << 6) + co);
            }
#pragma unroll
            for (int mi = 0; mi < 2; ++mi)
#pragma unroll
                for (int ni = 0; ni < 2; ++ni)
                    acc[mi][ni] = __builtin_amdgcn_mfma_f32_32x32x16_f16(
                        a[mi], bb[ni], acc[mi][ni], 0, 0, 0);
        }
        __syncthreads();
    }

#pragma unroll
    for (int ni = 0; ni < 2; ++ni) {
        int col = nB + wn + (ni << 5) + fr;
        float bv = dec_hf8((unsigned)bias_codes[col]);
#pragma unroll
        for (int mi = 0; mi < 2; ++mi) {
            int rbase = mB + wm + (mi << 5) + (kh << 2);
#pragma unroll
            for (int r = 0; r < 16; ++r) {
                int row = rbase + (r & 3) + ((r >> 2) << 3);
                C[(size_t)row * N + col] = acc[mi][ni][r] + bv;
            }
        }
    }
}

// ---------------- correctness parachute ----------------
__global__ void naive_kernel(const float* __restrict__ X, const int* __restrict__ Wc,
                             const int* __restrict__ Bc, float* __restrict__ C,
                             int M, int N, int K) {
    long long idx = (long long)blockIdx.x * 256 + threadIdx.x;
    if (idx >= (long long)M * N) return;
    int m = (int)(idx / N);
    int n = (int)(idx % N);
    float s = dec_hf8((unsigned)Bc[n]);
    const float* x = X + (size_t)m * K;
    const int* w = Wc + (size_t)n * K;
    for (int k = 0; k < K; ++k) s += x[k] * dec_hf8((unsigned)w[k]);
    C[idx] = s;
}

extern "C" void kernel_launch(void* const* d_in, const int* in_sizes, int n_in,
                              void* d_out, int out_size, void* d_ws, size_t ws_size,
                              hipStream_t stream) {
    const float* X  = (const float*)d_in[0];   // x: fp16 promoted to fp32 by harness
    const int*   Wc = (const int*)d_in[1];     // weight codes as int32
    const int*   Bc = (const int*)d_in[2];     // bias codes as int32
    float* C = (float*)d_out;

    long long wn = (long long)in_sizes[1];     // D_OUT * D_IN
    int N = in_sizes[2];                       // D_OUT
    int K = (int)(wn / N);                     // D_IN
    long long xn = (long long)in_sizes[0];
    int M = (int)(xn / K);                     // B*S

    size_t needXh = (size_t)xn * sizeof(_Float16);
    size_t needWh = (size_t)wn * sizeof(_Float16);
    size_t needW8 = (size_t)wn;

    bool ok8 = (M % 256 == 0) && (N % 256 == 0) && (K % 64 == 0) &&
               (wn % 16 == 0) && (xn % 8 == 0) &&
               (ws_size >= ((needXh + 15) & ~(size_t)15) + needWh + 16);
    bool okOld = (M % 128 == 0) && (N % 256 == 0) && (K % 64 == 0) &&
                 (wn % 16 == 0) && (xn % 8 == 0) &&
                 (ws_size >= needW8 + needXh + 16);

    if (ok8) {
        _Float16* Xh = (_Float16*)d_ws;
        _Float16* Wh = (_Float16*)((char*)d_ws + ((needXh + 15) & ~(size_t)15));
        cvt_x<<<dim3((unsigned)((xn / 8 + 255) / 256)), dim3(256), 0, stream>>>(X, Xh, xn / 8);
        decode_w<<<dim3((unsigned)((wn / 16 + 255) / 256)), dim3(256), 0, stream>>>(
            Wc, Wh, wn / 16);
        unsigned blocks = (unsigned)((M / 256) * (N / 256));
        hgemm_8ph<<<dim3(blocks), dim3(512), 0, stream>>>(Xh, Wh, Bc, C, M, N, K);
    } else if (okOld) {
        unsigned char* W8 = (unsigned char*)d_ws;
        _Float16* Xh = (_Float16*)((char*)d_ws + ((needW8 + 15) & ~(size_t)15));
        repack_codes<<<dim3((unsigned)((wn / 16 + 255) / 256)), dim3(256), 0, stream>>>(
            Wc, (unsigned*)W8, wn / 16);
        cvt_x<<<dim3((unsigned)((xn / 8 + 255) / 256)), dim3(256), 0, stream>>>(X, Xh, xn / 8);
        unsigned blocks = (unsigned)((M / 128) * (N / 256));
        hgemm_x2<<<dim3(blocks), dim3(512), 0, stream>>>(Xh, W8, Bc, C, M, N, K);
    } else {
        long long total = (long long)M * N;
        naive_kernel<<<dim3((unsigned)((total + 255) / 256)), dim3(256), 0, stream>>>(
            X, Wc, Bc, C, M, N, K);
    }
}

// Round 2
// 724.258 us; speedup vs baseline: 1.0125x; 1.0125x over previous
//
#include <hip/hip_runtime.h>
#include <cstdint>
#include <cstddef>

typedef _Float16 half8 __attribute__((ext_vector_type(8)));
typedef __fp16 fp16x2 __attribute__((ext_vector_type(2)));
typedef float f32x16 __attribute__((ext_vector_type(16)));
typedef float f32x2 __attribute__((ext_vector_type(2)));

// ---------------- hf8 decode (scalar, f32) ----------------
// code: sign(1) | e(4, bias 7) | m(3). e==0 -> m * 2^-9 ; else (1+m/8)*2^(e-7).
// Bit-identical to OCP e4m3fn except 0x7F/0xFF (|x|=480 vs NaN) — unreachable
// for this problem's data (|w| <= ~0.16).
__device__ __forceinline__ float dec_hf8(unsigned c) {
    unsigned e = (c >> 3) & 0xFu;
    unsigned m = c & 7u;
    float normal = __uint_as_float(((e + 120u) << 23) | (m << 20));
    float sub = (float)m * 0x1p-9f;
    float mag = (e != 0u) ? normal : sub;
    return (c & 0x80u) ? -mag : mag;
}

// decode 8 e4m3 codes (two packed words) -> 8 fp16, exact
__device__ __forceinline__ half8 dec8(unsigned w0, unsigned w1) {
#if __has_builtin(__builtin_amdgcn_cvt_pk_f32_fp8) && __has_builtin(__builtin_amdgcn_cvt_pkrtz)
    f32x2 a0 = __builtin_amdgcn_cvt_pk_f32_fp8((int)w0, false);
    f32x2 a1 = __builtin_amdgcn_cvt_pk_f32_fp8((int)w0, true);
    f32x2 a2 = __builtin_amdgcn_cvt_pk_f32_fp8((int)w1, false);
    f32x2 a3 = __builtin_amdgcn_cvt_pk_f32_fp8((int)w1, true);
    fp16x2 h0 = __builtin_amdgcn_cvt_pkrtz(a0.x, a0.y);  // exact: e4m3 subset of f16
    fp16x2 h1 = __builtin_amdgcn_cvt_pkrtz(a1.x, a1.y);
    fp16x2 h2 = __builtin_amdgcn_cvt_pkrtz(a2.x, a2.y);
    fp16x2 h3 = __builtin_amdgcn_cvt_pkrtz(a3.x, a3.y);
    half8 r = {(_Float16)h0.x, (_Float16)h0.y, (_Float16)h1.x, (_Float16)h1.y,
               (_Float16)h2.x, (_Float16)h2.y, (_Float16)h3.x, (_Float16)h3.y};
    return r;
#else
    half8 r;
#pragma unroll
    for (int i = 0; i < 4; ++i) r[i] = (_Float16)dec_hf8((w0 >> (8 * i)) & 0xFFu);
#pragma unroll
    for (int i = 0; i < 4; ++i) r[4 + i] = (_Float16)dec_hf8((w1 >> (8 * i)) & 0xFFu);
    return r;
#endif
}

// ---------------- prep A (new path): decode W codes int32 -> fp16 ----------------
__global__ __launch_bounds__(256) void decode_w(const int* __restrict__ codes,
                                                _Float16* __restrict__ out,
                                                long long n16) {
    long long i = (long long)blockIdx.x * 256 + threadIdx.x;
    if (i >= n16) return;
    long long base = i * 16;
    unsigned w[4];
#pragma unroll
    for (int q = 0; q < 4; ++q) {
        int4 c = *(const int4*)(codes + base + q * 4);
        w[q] = ((unsigned)c.x & 255u) | (((unsigned)c.y & 255u) << 8) |
               (((unsigned)c.z & 255u) << 16) | (((unsigned)c.w & 255u) << 24);
    }
    *(half8*)(out + base) = dec8(w[0], w[1]);
    *(half8*)(out + base + 8) = dec8(w[2], w[3]);
}

// ---------------- prep (old path): repack weight codes int32 -> uint8 ----------------
__global__ __launch_bounds__(256) void repack_codes(const int* __restrict__ codes,
                                                    unsigned* __restrict__ out,
                                                    long long n16) {
    long long i = (long long)blockIdx.x * 256 + threadIdx.x;
    if (i >= n16) return;
    long long base = i * 16;
    unsigned w[4];
#pragma unroll
    for (int q = 0; q < 4; ++q) {
        int4 c = *(const int4*)(codes + base + q * 4);
        w[q] = ((unsigned)c.x & 255u) | (((unsigned)c.y & 255u) << 8) |
               (((unsigned)c.z & 255u) << 16) | (((unsigned)c.w & 255u) << 24);
    }
    *(uint4*)(out + i * 4) = make_uint4(w[0], w[1], w[2], w[3]);
}

// ---------------- prep: X fp32 -> fp16 ----------------
__global__ __launch_bounds__(256) void cvt_x(const float* __restrict__ X,
                                             _Float16* __restrict__ out,
                                             long long n8) {
    long long i = (long long)blockIdx.x * 256 + threadIdx.x;
    if (i >= n8) return;
    long long base = i * 8;
    float4 v0 = *(const float4*)(X + base);
    float4 v1 = *(const float4*)(X + base + 4);
    half8 h = {(_Float16)v0.x, (_Float16)v0.y, (_Float16)v0.z, (_Float16)v0.w,
               (_Float16)v1.x, (_Float16)v1.y, (_Float16)v1.z, (_Float16)v1.w};
    *(half8*)(out + base) = h;
}

// ---------------- async global->LDS (16B/lane, wave-uniform LDS base) ----------------
__device__ __forceinline__ void gl_lds16(const void* g, void* l) {
    __builtin_amdgcn_global_load_lds(
        (__attribute__((address_space(1))) void*)(g),
        (__attribute__((address_space(3))) void*)(l), 16, 0, 0);
}

// per-row LDS XOR key (verified conflict-free + correct in previous rounds)
#define FKEY(r) (((r) ^ ((r) >> 3)) & 7)

// raw barrier (no vmcnt/lgkm drain) + compiler memory fence both sides
#define BAR()                                  \
    {                                          \
        asm volatile("" ::: "memory");         \
        __builtin_amdgcn_s_barrier();          \
        asm volatile("" ::: "memory");         \
    }

// ================= 4-phase 256x256 GEMM, register-held fragments ==================
// C = Xh[M][K] * Wh[N][K]^T + bias. BK=64, 8 waves (2m x 4n), wave tile 128x64.
// LDS 128KB: A/B each [2 dbuf][2 half][128 rows][64 f16], FKEY-swizzled chunks.
// KEY CHANGE vs previous round: fragments are READ ONCE per K-tile and held in
// registers across phases (regs survive barriers):
//   ph1 (A0,B0): read a[8] (A-half0) + b0[4]   -> 12 ds_read_b128
//   ph2 (A0,B1): read b1[4]                    ->  4
//   ph3 (A1,B0): read a[8] (A-half1, overwrite)->  8
//   ph4 (A1,B1): no reads                      ->  0
// LDS reads/K-tile: 384 KB -> 192 KB (the 8-wave minimum for a 256^2 tile);
// previous round's counters showed LDS read BW (~85 B/cyc/CU for b128) was the
// binding resource (448 KB ~ 5300 cyc vs MFMA floor 2066 cyc of 6270 measured).
// Staging lifetimes (re-derived): A1/B1(t+1) staged ph1/ph2 (other buffer, safe);
// A0/B0(t+2) staged ph3/ph4 (same buffer, last read ph1 -> >=1 full phase gap).
// Boundary vmcnt(4) completes exactly the 4 halves needed for iter t+1.
__global__ __launch_bounds__(512) void hgemm_8ph(const _Float16* __restrict__ Xh,
                                                 const _Float16* __restrict__ Wh,
                                                 const int* __restrict__ bias_codes,
                                                 float* __restrict__ C,
                                                 int M, int N, int K) {
    __shared__ _Float16 As[2][2][128 * 64];
    __shared__ _Float16 Bs[2][2][128 * 64];

    const int tid  = threadIdx.x;
    const int lane = tid & 63;
    const int wid  = tid >> 6;

    const int nT = N >> 8;
    const int mT = M >> 8;
    int mTile, nTile;
    int bid = blockIdx.x;
    if (mT == 16) {                  // XCD map: XCD x owns m-band {2x,2x+1} x all n
        int x = bid & 7;             // bid%8 == XCD round-robin heuristic
        int l = bid >> 3;            // 0 .. 2*nT-1
        mTile = (x << 1) + (l & 1);  // 2 m-tiles share each XCD's 4MB L2 X-band
        nTile = l >> 1;              // consecutive bids share the W panel
    } else {
        mTile = bid / nT;
        nTile = bid % nT;
    }
    const int mB = mTile << 8;
    const int nB = nTile << 8;
    const int kIters = K >> 6;

    // ---- staging source geometry: thread stages rows srow and srow+64 of a half
    const int    srow = tid >> 3;                       // 0..63
    const int    sg   = (tid & 7) ^ FKEY(srow);         // swizzled source chunk
    const size_t soff = (size_t)srow * K + ((size_t)sg << 3);
    const size_t rowStep = (size_t)K << 6;              // +64 rows (FKEY(r+64)==FKEY(r))
    const _Float16* aS0 = Xh + (size_t)mB * K + soff;
    const _Float16* aS1 = Xh + (size_t)(mB + 128) * K + soff;
    const _Float16* bS0 = Wh + (size_t)nB * K + soff;
    const _Float16* bS1 = Wh + (size_t)(nB + 128) * K + soff;

#define STG(SRC, DSTARR, tt, half_)                                   \
    {                                                                 \
        char* d_ = (char*)(&DSTARR[(tt) & 1][half_][0]);              \
        const _Float16* s_ = (SRC) + ((size_t)(tt) << 6);             \
        gl_lds16(s_, d_ + (tid << 4));                                \
        gl_lds16(s_ + rowStep, d_ + ((512 + tid) << 4));              \
    }

    // ---- fragment geometry (identical to verified pattern)
    const int wm   = wid >> 2;                 // 0..1
    const int wn   = wid & 3;                  // 0..3
    const int fr   = lane & 31;
    const int kh   = lane >> 5;
    const int fkey = FKEY(fr);
    const int lrA0 = (wm << 6) + fr;           // local A row (half-relative), +32 for i=1
    const int lrB  = (wn << 5) + fr;           // local B row (half-relative)
    const int keyB = fkey ^ ((wn & 1) << 2);

    f32x16 acc[2][2][2] = {};  // [MH][i][NH], all indices compile-time after unroll

#define MFMA_QUAD(MH, NH, BV)                                                   \
    {                                                                           \
        __builtin_amdgcn_s_setprio(1);                                          \
        _Pragma("unroll") for (int ks = 0; ks < 4; ++ks) {                      \
            acc[MH][0][NH] = __builtin_amdgcn_mfma_f32_32x32x16_f16(            \
                a[ks], BV[ks], acc[MH][0][NH], 0, 0, 0);                        \
            acc[MH][1][NH] = __builtin_amdgcn_mfma_f32_32x32x16_f16(            \
                a[4 + ks], BV[ks], acc[MH][1][NH], 0, 0, 0);                    \
        }                                                                       \
        __builtin_amdgcn_s_setprio(0);                                          \
    }

    // ---- prologue: stage tile0 (4 halves) + tile1's A0/B0, counted wait
    STG(aS0, As, 0, 0);
    STG(bS0, Bs, 0, 0);
    STG(aS1, As, 0, 1);
    STG(bS1, Bs, 0, 1);
    if (kIters > 1) {
        STG(aS0, As, 1, 0);
        STG(bS0, Bs, 1, 0);
        asm volatile("s_waitcnt vmcnt(4)" ::: "memory");  // tile0 landed; A0/B0(1) in flight
    } else {
        asm volatile("s_waitcnt vmcnt(0)" ::: "memory");
    }
    BAR();

    for (int t = 0; t < kIters; ++t) {
        const int buf = t & 1;
        const _Float16* A0b = &As[buf][0][0];
        const _Float16* A1b = &As[buf][1][0];
        const _Float16* B0b = &Bs[buf][0][0];
        const _Float16* B1b = &Bs[buf][1][0];
        half8 a[8], b0[4], b1[4];

        // ---- phase 1: (A0,B0) — read a (A-half0) + b0
#pragma unroll
        for (int ks = 0; ks < 4; ++ks) {
            const int lc = (ks << 1) + kh;
            a[ks]     = *(const half8*)(A0b + (lrA0 << 6) + ((lc ^ fkey) << 3));
            a[4 + ks] = *(const half8*)(A0b + ((lrA0 + 32) << 6) + ((lc ^ fkey ^ 4) << 3));
            b0[ks]    = *(const half8*)(B0b + (lrB << 6) + ((lc ^ keyB) << 3));
        }
        if (t + 1 < kIters) STG(aS1, As, t + 1, 1);
        BAR();
        MFMA_QUAD(0, 0, b0);
        BAR();

        // ---- phase 2: (A0,B1) — read b1, reuse a
#pragma unroll
        for (int ks = 0; ks < 4; ++ks) {
            const int lc = (ks << 1) + kh;
            b1[ks] = *(const half8*)(B1b + (lrB << 6) + ((lc ^ keyB) << 3));
        }
        if (t + 1 < kIters) STG(bS1, Bs, t + 1, 1);
        BAR();
        MFMA_QUAD(0, 1, b1);
        BAR();

        // ---- phase 3: (A1,B0) — read a (A-half1, overwrite), reuse b0
#pragma unroll
        for (int ks = 0; ks < 4; ++ks) {
            const int lc = (ks << 1) + kh;
            a[ks]     = *(const half8*)(A1b + (lrA0 << 6) + ((lc ^ fkey) << 3));
            a[4 + ks] = *(const half8*)(A1b + ((lrA0 + 32) << 6) + ((lc ^ fkey ^ 4) << 3));
        }
        if (t + 2 < kIters) STG(aS0, As, t + 2, 0);
        BAR();
        MFMA_QUAD(1, 0, b0);
        BAR();

        // ---- phase 4: (A1,B1) — no reads, reuse a + b1
        if (t + 2 < kIters) STG(bS0, Bs, t + 2, 0);
        BAR();
        MFMA_QUAD(1, 1, b1);
        if (t + 2 < kIters) {
            asm volatile("s_waitcnt vmcnt(4)" ::: "memory");  // completes t+1 halves
        } else if (t + 1 < kIters) {
            asm volatile("s_waitcnt vmcnt(0)" ::: "memory");  // entering last tile
        }
        BAR();
    }

#undef MFMA_QUAD
#undef STG

    // ---- epilogue: col = lane&31, row = (reg&3) + 8*(reg>>2) + 4*(lane>>5) [m74/m101]
#pragma unroll
    for (int NH = 0; NH < 2; ++NH) {
        const int col = nB + (NH << 7) + (wn << 5) + fr;
        const float bv = dec_hf8((unsigned)bias_codes[col]);
#pragma unroll
        for (int MH = 0; MH < 2; ++MH)
#pragma unroll
            for (int i = 0; i < 2; ++i) {
                const int rbase = mB + (MH << 7) + (wm << 6) + (i << 5) + (kh << 2);
#pragma unroll
                for (int r = 0; r < 16; ++r) {
                    const int row = rbase + (r & 3) + ((r >> 2) << 3);
                    C[(size_t)row * N + col] = acc[MH][i][NH][r] + bv;
                }
            }
    }
}

// ================= fallback GEMM (previous verified kernel, 128x256 tile) =========
__global__ __launch_bounds__(512) void hgemm_x2(const _Float16* __restrict__ Xh,
                                                const unsigned char* __restrict__ W8,
                                                const int* __restrict__ bias_codes,
                                                float* __restrict__ C,
                                                int M, int N, int K) {
    __shared__ _Float16 As[128 * 64];
    __shared__ _Float16 Bs[256 * 64];

    const int tid  = threadIdx.x;
    const int lane = tid & 63;
    const int wid  = tid >> 6;

    const int nT = N >> 8;
    const int mT = M >> 7;
    int mTile, nTile;
    int bid = blockIdx.x;
    if (mT == 32) {
        int x = bid & 7;
        int l = bid >> 3;
        mTile = (x << 2) + (l & 3);
        nTile = l >> 2;
    } else {
        mTile = bid / nT;
        nTile = bid % nT;
    }
    const int mB = mTile << 7;
    const int nB = nTile << 8;

    const int kIters = K >> 6;

    const _Float16* aptr[2];
#pragma unroll
    for (int it = 0; it < 2; ++it) {
        int p = it * 512 + tid;
        int row = p >> 3;
        int g = (p & 7) ^ FKEY(row);
        aptr[it] = Xh + (size_t)(mB + row) * K + (g << 3);
    }
    char* as_base = (char*)As;

    const int brow = tid >> 1;
    const int bhc  = tid & 1;
    const unsigned char* bptr = W8 + (size_t)(nB + brow) * K + (bhc << 5);
    const int bfk = FKEY(brow);
    _Float16* brow_lds = Bs + (brow << 6);
    const int bg0 = bhc << 2;

    const int wm = (wid >> 2) << 6;
    const int wn = (wid & 3) << 6;
    const int fr = lane & 31;
    const int kh = lane >> 5;
    const int fkey = FKEY(fr);

    f32x16 acc[2][2] = {};

    for (int kt = 0; kt < kIters; ++kt) {
#pragma unroll
        for (int it = 0; it < 2; ++it) {
            gl_lds16(aptr[it], as_base + ((it * 512 + tid) << 4));
            aptr[it] += 64;
        }
        uint4 q0 = *(const uint4*)(bptr);
        uint4 q1 = *(const uint4*)(bptr + 16);
        bptr += 64;
        half8 d0 = dec8(q0.x, q0.y);
        half8 d1 = dec8(q0.z, q0.w);
        half8 d2 = dec8(q1.x, q1.y);
        half8 d3 = dec8(q1.z, q1.w);
        *(half8*)(brow_lds + (((bg0 + 0) ^ bfk) << 3)) = d0;
        *(half8*)(brow_lds + (((bg0 + 1) ^ bfk) << 3)) = d1;
        *(half8*)(brow_lds + (((bg0 + 2) ^ bfk) << 3)) = d2;
        *(half8*)(brow_lds + (((bg0 + 3) ^ bfk) << 3)) = d3;
        __syncthreads();

#pragma unroll
        for (int ks = 0; ks < 4; ++ks) {
            const int lc = (ks << 1) + kh;
            half8 a[2], bb[2];
#pragma unroll
            for (int i = 0; i < 2; ++i) {
                const int co = ((lc ^ fkey ^ (i << 2)) << 3);
                a[i]  = *(const half8*)(As + ((wm + (i << 5) + fr) << 6) + co);
                bb[i] = *(const half8*)(Bs + ((wn + (i << 5) + fr) << 6) + co);
            }
#pragma unroll
            for (int mi = 0; mi < 2; ++mi)
#pragma unroll
                for (int ni = 0; ni < 2; ++ni)
                    acc[mi][ni] = __builtin_amdgcn_mfma_f32_32x32x16_f16(
                        a[mi], bb[ni], acc[mi][ni], 0, 0, 0);
        }
        __syncthreads();
    }

#pragma unroll
    for (int ni = 0; ni < 2; ++ni) {
        int col = nB + wn + (ni << 5) + fr;
        float bv = dec_hf8((unsigned)bias_codes[col]);
#pragma unroll
        for (int mi = 0; mi < 2; ++mi) {
            int rbase = mB + wm + (mi << 5) + (kh << 2);
#pragma unroll
            for (int r = 0; r < 16; ++r) {
                int row = rbase + (r & 3) + ((r >> 2) << 3);
                C[(size_t)row * N + col] = acc[mi][ni][r] + bv;
            }
        }
    }
}

// ---------------- correctness parachute ----------------
__global__ void naive_kernel(const float* __restrict__ X, const int* __restrict__ Wc,
                             const int* __restrict__ Bc, float* __restrict__ C,
                             int M, int N, int K) {
    long long idx = (long long)blockIdx.x * 256 + threadIdx.x;
    if (idx >= (long long)M * N) return;
    int m = (int)(idx / N);
    int n = (int)(idx % N);
    float s = dec_hf8((unsigned)Bc[n]);
    const float* x = X + (size_t)m * K;
    const int* w = Wc + (size_t)n * K;
    for (int k = 0; k < K; ++k) s += x[k] * dec_hf8((unsigned)w[k]);
    C[idx] = s;
}

extern "C" void kernel_launch(void* const* d_in, const int* in_sizes, int n_in,
                              void* d_out, int out_size, void* d_ws, size_t ws_size,
                              hipStream_t stream) {
    const float* X  = (const float*)d_in[0];   // x: fp16 promoted to fp32 by harness
    const int*   Wc = (const int*)d_in[1];     // weight codes as int32
    const int*   Bc = (const int*)d_in[2];     // bias codes as int32
    float* C = (float*)d_out;

    long long wn = (long long)in_sizes[1];     // D_OUT * D_IN
    int N = in_sizes[2];                       // D_OUT
    int K = (int)(wn / N);                     // D_IN
    long long xn = (long long)in_sizes[0];
    int M = (int)(xn / K);                     // B*S

    size_t needXh = (size_t)xn * sizeof(_Float16);
    size_t needWh = (size_t)wn * sizeof(_Float16);
    size_t needW8 = (size_t)wn;

    bool ok8 = (M % 256 == 0) && (N % 256 == 0) && (K % 64 == 0) &&
               (wn % 16 == 0) && (xn % 8 == 0) &&
               (ws_size >= ((needXh + 15) & ~(size_t)15) + needWh + 16);
    bool okOld = (M % 128 == 0) && (N % 256 == 0) && (K % 64 == 0) &&
                 (wn % 16 == 0) && (xn % 8 == 0) &&
                 (ws_size >= needW8 + needXh + 16);

    if (ok8) {
        _Float16* Xh = (_Float16*)d_ws;
        _Float16* Wh = (_Float16*)((char*)d_ws + ((needXh + 15) & ~(size_t)15));
        cvt_x<<<dim3((unsigned)((xn / 8 + 255) / 256)), dim3(256), 0, stream>>>(X, Xh, xn / 8);
        decode_w<<<dim3((unsigned)((wn / 16 + 255) / 256)), dim3(256), 0, stream>>>(
            Wc, Wh, wn / 16);
        unsigned blocks = (unsigned)((M / 256) * (N / 256));
        hgemm_8ph<<<dim3(blocks), dim3(512), 0, stream>>>(Xh, Wh, Bc, C, M, N, K);
    } else if (okOld) {
        unsigned char* W8 = (unsigned char*)d_ws;
        _Float16* Xh = (_Float16*)((char*)d_ws + ((needW8 + 15) & ~(size_t)15));
        repack_codes<<<dim3((unsigned)((wn / 16 + 255) / 256)), dim3(256), 0, stream>>>(
            Wc, (unsigned*)W8, wn / 16);
        cvt_x<<<dim3((unsigned)((xn / 8 + 255) / 256)), dim3(256), 0, stream>>>(X, Xh, xn / 8);
        unsigned blocks = (unsigned)((M / 128) * (N / 256));
        hgemm_x2<<<dim3(blocks), dim3(512), 0, stream>>>(Xh, W8, Bc, C, M, N, K);
    } else {
        long long total = (long long)M * N;
        naive_kernel<<<dim3((unsigned)((total + 255) / 256)), dim3(256), 0, stream>>>(
            X, Wc, Bc, C, M, N, K);
    }
}

// Round 3
// 691.948 us; speedup vs baseline: 1.0598x; 1.0467x over previous
//
#include <hip/hip_runtime.h>
#include <cstdint>
#include <cstddef>

typedef _Float16 half8 __attribute__((ext_vector_type(8)));
typedef __fp16 fp16x2 __attribute__((ext_vector_type(2)));
typedef float f32x16 __attribute__((ext_vector_type(16)));
typedef float f32x2 __attribute__((ext_vector_type(2)));

// ---------------- hf8 decode (scalar, f32) ----------------
// code: sign(1) | e(4, bias 7) | m(3). e==0 -> m * 2^-9 ; else (1+m/8)*2^(e-7).
// Bit-identical to OCP e4m3fn except 0x7F/0xFF (|x|=480 vs NaN) — unreachable
// for this problem's data (|w| <= ~0.16).
__device__ __forceinline__ float dec_hf8(unsigned c) {
    unsigned e = (c >> 3) & 0xFu;
    unsigned m = c & 7u;
    float normal = __uint_as_float(((e + 120u) << 23) | (m << 20));
    float sub = (float)m * 0x1p-9f;
    float mag = (e != 0u) ? normal : sub;
    return (c & 0x80u) ? -mag : mag;
}

// decode 8 e4m3 codes (two packed words) -> 8 fp16, exact
__device__ __forceinline__ half8 dec8(unsigned w0, unsigned w1) {
#if __has_builtin(__builtin_amdgcn_cvt_pk_f32_fp8) && __has_builtin(__builtin_amdgcn_cvt_pkrtz)
    f32x2 a0 = __builtin_amdgcn_cvt_pk_f32_fp8((int)w0, false);
    f32x2 a1 = __builtin_amdgcn_cvt_pk_f32_fp8((int)w0, true);
    f32x2 a2 = __builtin_amdgcn_cvt_pk_f32_fp8((int)w1, false);
    f32x2 a3 = __builtin_amdgcn_cvt_pk_f32_fp8((int)w1, true);
    fp16x2 h0 = __builtin_amdgcn_cvt_pkrtz(a0.x, a0.y);  // exact: e4m3 subset of f16
    fp16x2 h1 = __builtin_amdgcn_cvt_pkrtz(a1.x, a1.y);
    fp16x2 h2 = __builtin_amdgcn_cvt_pkrtz(a2.x, a2.y);
    fp16x2 h3 = __builtin_amdgcn_cvt_pkrtz(a3.x, a3.y);
    half8 r = {(_Float16)h0.x, (_Float16)h0.y, (_Float16)h1.x, (_Float16)h1.y,
               (_Float16)h2.x, (_Float16)h2.y, (_Float16)h3.x, (_Float16)h3.y};
    return r;
#else
    half8 r;
#pragma unroll
    for (int i = 0; i < 4; ++i) r[i] = (_Float16)dec_hf8((w0 >> (8 * i)) & 0xFFu);
#pragma unroll
    for (int i = 0; i < 4; ++i) r[4 + i] = (_Float16)dec_hf8((w1 >> (8 * i)) & 0xFFu);
    return r;
#endif
}

// ---------------- prep A (new path): decode W codes int32 -> fp16 ----------------
__global__ __launch_bounds__(256) void decode_w(const int* __restrict__ codes,
                                                _Float16* __restrict__ out,
                                                long long n16) {
    long long i = (long long)blockIdx.x * 256 + threadIdx.x;
    if (i >= n16) return;
    long long base = i * 16;
    unsigned w[4];
#pragma unroll
    for (int q = 0; q < 4; ++q) {
        int4 c = *(const int4*)(codes + base + q * 4);
        w[q] = ((unsigned)c.x & 255u) | (((unsigned)c.y & 255u) << 8) |
               (((unsigned)c.z & 255u) << 16) | (((unsigned)c.w & 255u) << 24);
    }
    *(half8*)(out + base) = dec8(w[0], w[1]);
    *(half8*)(out + base + 8) = dec8(w[2], w[3]);
}

// ---------------- prep (old path): repack weight codes int32 -> uint8 ----------------
__global__ __launch_bounds__(256) void repack_codes(const int* __restrict__ codes,
                                                    unsigned* __restrict__ out,
                                                    long long n16) {
    long long i = (long long)blockIdx.x * 256 + threadIdx.x;
    if (i >= n16) return;
    long long base = i * 16;
    unsigned w[4];
#pragma unroll
    for (int q = 0; q < 4; ++q) {
        int4 c = *(const int4*)(codes + base + q * 4);
        w[q] = ((unsigned)c.x & 255u) | (((unsigned)c.y & 255u) << 8) |
               (((unsigned)c.z & 255u) << 16) | (((unsigned)c.w & 255u) << 24);
    }
    *(uint4*)(out + i * 4) = make_uint4(w[0], w[1], w[2], w[3]);
}

// ---------------- prep: X fp32 -> fp16 ----------------
__global__ __launch_bounds__(256) void cvt_x(const float* __restrict__ X,
                                             _Float16* __restrict__ out,
                                             long long n8) {
    long long i = (long long)blockIdx.x * 256 + threadIdx.x;
    if (i >= n8) return;
    long long base = i * 8;
    float4 v0 = *(const float4*)(X + base);
    float4 v1 = *(const float4*)(X + base + 4);
    half8 h = {(_Float16)v0.x, (_Float16)v0.y, (_Float16)v0.z, (_Float16)v0.w,
               (_Float16)v1.x, (_Float16)v1.y, (_Float16)v1.z, (_Float16)v1.w};
    *(half8*)(out + base) = h;
}

// ---------------- async global->LDS (16B/lane, wave-uniform LDS base) ----------------
__device__ __forceinline__ void gl_lds16(const void* g, void* l) {
    __builtin_amdgcn_global_load_lds(
        (__attribute__((address_space(1))) void*)(g),
        (__attribute__((address_space(3))) void*)(l), 16, 0, 0);
}

// per-row LDS XOR key (verified conflict-free + correct in previous rounds)
#define FKEY(r) (((r) ^ ((r) >> 3)) & 7)

// raw barrier (no vmcnt/lgkm drain) + compiler memory fence both sides
#define BAR()                                  \
    {                                          \
        asm volatile("" ::: "memory");         \
        __builtin_amdgcn_s_barrier();          \
        asm volatile("" ::: "memory");         \
    }

// ================= 2-phase 256x256 GEMM, register-held fragments ==================
// C = Xh[M][K] * Wh[N][K]^T + bias. BK=64, 8 waves (2m x 4n), wave tile 128x64.
// LDS 128KB: A/B each [2 dbuf][2 half][128 rows][64 f16], FKEY-swizzled chunks.
// ROUND-3 CHANGE: rounds 1-2 measured ~6000 cyc/K-tile with MFMA floor 2066 and
// LDS work ~2000 -> ~2500 cyc of sync dead time from 8 barriers/K-tile and
// per-phase 4-deep acc-chain drain (post-MFMA barrier forced chain latency onto
// the critical path every phase). New structure: 2 phases, 3 barriers/K-tile,
// 16-MFMA clusters (4 independent 4-deep chains), NO post-cluster barrier --
// cluster tails drain in the matrix pipe while the next phase's ds_reads issue
// (consecutive clusters touch disjoint accumulators -> no interlock).
// Per-tile order and safety proof (DMA-write vs LDS-read races):
//   R1 (a<-A0 8, b0<-B0 4, b1<-B1 4) ; S1: STG A1,B1(t+1)->buf^1 ; B1barrier
//   M1 (A0 x {B0,B1}, 16 mfma) [sched_barrier pins M1 before R2]
//   R2 (a<-A1 8) ; B2barrier ; S2: STG A0,B0(t+2)->same buf ; M2 (A1 x {B0,B1})
//   vmcnt(4) ; B3barrier
// * S2 safe: all waves passed B2 => all issued M1 (pinned) => all R1 reads of
//   A0/B0 consumed before any S2 DMA can land.
// * S1 safe: regions A1/B1 of buf^1 were last read in tile t-1 (R2/R1), consumed
//   before M2(t-1)/M1(t-1), which precede boundary B3(t-1).
// * vmcnt(4) at boundary completes the 8 oldest of 12 outstanding gl_lds =
//   S2(t-1)[A0,B0(t+1)] + S1(t)[A1,B1(t+1)] = exactly tile t+1's four halves.
__global__ __launch_bounds__(512) void hgemm_8ph(const _Float16* __restrict__ Xh,
                                                 const _Float16* __restrict__ Wh,
                                                 const int* __restrict__ bias_codes,
                                                 float* __restrict__ C,
                                                 int M, int N, int K) {
    __shared__ _Float16 As[2][2][128 * 64];
    __shared__ _Float16 Bs[2][2][128 * 64];

    const int tid  = threadIdx.x;
    const int lane = tid & 63;
    const int wid  = tid >> 6;

    const int nT = N >> 8;
    const int mT = M >> 8;
    int mTile, nTile;
    int bid = blockIdx.x;
    if (mT == 16) {                  // XCD map: XCD x owns m-band {2x,2x+1} x all n
        int x = bid & 7;             // bid%8 == XCD round-robin heuristic
        int l = bid >> 3;            // 0 .. 2*nT-1
        mTile = (x << 1) + (l & 1);  // 2 m-tiles share each XCD's 4MB L2 X-band
        nTile = l >> 1;              // consecutive bids share the W panel
    } else {
        mTile = bid / nT;
        nTile = bid % nT;
    }
    const int mB = mTile << 8;
    const int nB = nTile << 8;
    const int kIters = K >> 6;

    // ---- staging source geometry: thread stages rows srow and srow+64 of a half
    const int    srow = tid >> 3;                       // 0..63
    const int    sg   = (tid & 7) ^ FKEY(srow);         // swizzled source chunk
    const size_t soff = (size_t)srow * K + ((size_t)sg << 3);
    const size_t rowStep = (size_t)K << 6;              // +64 rows (FKEY(r+64)==FKEY(r))
    const _Float16* aS0 = Xh + (size_t)mB * K + soff;
    const _Float16* aS1 = Xh + (size_t)(mB + 128) * K + soff;
    const _Float16* bS0 = Wh + (size_t)nB * K + soff;
    const _Float16* bS1 = Wh + (size_t)(nB + 128) * K + soff;

#define STG(SRC, DSTARR, tt, half_)                                   \
    {                                                                 \
        char* d_ = (char*)(&DSTARR[(tt) & 1][half_][0]);              \
        const _Float16* s_ = (SRC) + ((size_t)(tt) << 6);             \
        gl_lds16(s_, d_ + (tid << 4));                                \
        gl_lds16(s_ + rowStep, d_ + ((512 + tid) << 4));              \
    }

    // ---- fragment geometry (identical to verified pattern)
    const int wm   = wid >> 2;                 // 0..1
    const int wn   = wid & 3;                  // 0..3
    const int fr   = lane & 31;
    const int kh   = lane >> 5;
    const int fkey = FKEY(fr);
    const int lrA0 = (wm << 6) + fr;           // local A row (half-relative), +32 for i=1
    const int lrB  = (wn << 5) + fr;           // local B row (half-relative)
    const int keyB = fkey ^ ((wn & 1) << 2);

    f32x16 acc[2][2][2] = {};  // [MH][i][NH], all indices compile-time after unroll

#define MFMA_CLUSTER(MH)                                                        \
    {                                                                           \
        __builtin_amdgcn_s_setprio(1);                                          \
        _Pragma("unroll") for (int ks = 0; ks < 4; ++ks) {                      \
            acc[MH][0][0] = __builtin_amdgcn_mfma_f32_32x32x16_f16(             \
                a[ks], b0[ks], acc[MH][0][0], 0, 0, 0);                         \
            acc[MH][1][0] = __builtin_amdgcn_mfma_f32_32x32x16_f16(             \
                a[4 + ks], b0[ks], acc[MH][1][0], 0, 0, 0);                     \
            acc[MH][0][1] = __builtin_amdgcn_mfma_f32_32x32x16_f16(             \
                a[ks], b1[ks], acc[MH][0][1], 0, 0, 0);                         \
            acc[MH][1][1] = __builtin_amdgcn_mfma_f32_32x32x16_f16(             \
                a[4 + ks], b1[ks], acc[MH][1][1], 0, 0, 0);                     \
        }                                                                       \
        __builtin_amdgcn_s_setprio(0);                                          \
        __builtin_amdgcn_sched_barrier(0);                                      \
    }

    // ---- prologue: stage tile0 (4 halves) + tile1's A0/B0, counted wait
    STG(aS0, As, 0, 0);
    STG(bS0, Bs, 0, 0);
    STG(aS1, As, 0, 1);
    STG(bS1, Bs, 0, 1);
    if (kIters > 1) {
        STG(aS0, As, 1, 0);
        STG(bS0, Bs, 1, 0);
        asm volatile("s_waitcnt vmcnt(4)" ::: "memory");  // tile0 landed; A0/B0(1) in flight
    } else {
        asm volatile("s_waitcnt vmcnt(0)" ::: "memory");
    }
    BAR();

    for (int t = 0; t < kIters; ++t) {
        const int buf = t & 1;
        const _Float16* A0b = &As[buf][0][0];
        const _Float16* A1b = &As[buf][1][0];
        const _Float16* B0b = &Bs[buf][0][0];
        const _Float16* B1b = &Bs[buf][1][0];
        half8 a[8], b0[4], b1[4];

        // ---- phase 1 reads: A-half0 + BOTH B halves (16 x ds_read_b128)
#pragma unroll
        for (int ks = 0; ks < 4; ++ks) {
            const int lc = (ks << 1) + kh;
            a[ks]     = *(const half8*)(A0b + (lrA0 << 6) + ((lc ^ fkey) << 3));
            a[4 + ks] = *(const half8*)(A0b + ((lrA0 + 32) << 6) + ((lc ^ fkey ^ 4) << 3));
            b0[ks]    = *(const half8*)(B0b + (lrB << 6) + ((lc ^ keyB) << 3));
            b1[ks]    = *(const half8*)(B1b + (lrB << 6) + ((lc ^ keyB) << 3));
        }
        if (t + 1 < kIters) {            // S1: other buffer, safe (see proof above)
            STG(aS1, As, t + 1, 1);
            STG(bS1, Bs, t + 1, 1);
        }
        BAR();                           // B1
        MFMA_CLUSTER(0);                 // M1: A0 x {B0,B1}, pinned before R2

        // ---- phase 2 reads: A-half1 (8 x ds_read_b128), reuse b0/b1
#pragma unroll
        for (int ks = 0; ks < 4; ++ks) {
            const int lc = (ks << 1) + kh;
            a[ks]     = *(const half8*)(A1b + (lrA0 << 6) + ((lc ^ fkey) << 3));
            a[4 + ks] = *(const half8*)(A1b + ((lrA0 + 32) << 6) + ((lc ^ fkey ^ 4) << 3));
        }
        BAR();                           // B2: certifies all waves consumed R1
        if (t + 2 < kIters) {            // S2: same buffer, safe only after B2
            STG(aS0, As, t + 2, 0);
            STG(bS0, Bs, t + 2, 0);
        }
        MFMA_CLUSTER(1);                 // M2: A1 x {B0,B1}

        if (t + 2 < kIters) {
            asm volatile("s_waitcnt vmcnt(4)" ::: "memory");  // completes t+1 halves
        } else if (t + 1 < kIters) {
            asm volatile("s_waitcnt vmcnt(0)" ::: "memory");  // entering last tile
        }
        BAR();                           // B3: boundary
    }

#undef MFMA_CLUSTER
#undef STG

    // ---- epilogue: col = lane&31, row = (reg&3) + 8*(reg>>2) + 4*(lane>>5) [m74/m101]
#pragma unroll
    for (int NH = 0; NH < 2; ++NH) {
        const int col = nB + (NH << 7) + (wn << 5) + fr;
        const float bv = dec_hf8((unsigned)bias_codes[col]);
#pragma unroll
        for (int MH = 0; MH < 2; ++MH)
#pragma unroll
            for (int i = 0; i < 2; ++i) {
                const int rbase = mB + (MH << 7) + (wm << 6) + (i << 5) + (kh << 2);
#pragma unroll
                for (int r = 0; r < 16; ++r) {
                    const int row = rbase + (r & 3) + ((r >> 2) << 3);
                    C[(size_t)row * N + col] = acc[MH][i][NH][r] + bv;
                }
            }
    }
}

// ================= fallback GEMM (previous verified kernel, 128x256 tile) =========
__global__ __launch_bounds__(512) void hgemm_x2(const _Float16* __restrict__ Xh,
                                                const unsigned char* __restrict__ W8,
                                                const int* __restrict__ bias_codes,
                                                float* __restrict__ C,
                                                int M, int N, int K) {
    __shared__ _Float16 As[128 * 64];
    __shared__ _Float16 Bs[256 * 64];

    const int tid  = threadIdx.x;
    const int lane = tid & 63;
    const int wid  = tid >> 6;

    const int nT = N >> 8;
    const int mT = M >> 7;
    int mTile, nTile;
    int bid = blockIdx.x;
    if (mT == 32) {
        int x = bid & 7;
        int l = bid >> 3;
        mTile = (x << 2) + (l & 3);
        nTile = l >> 2;
    } else {
        mTile = bid / nT;
        nTile = bid % nT;
    }
    const int mB = mTile << 7;
    const int nB = nTile << 8;

    const int kIters = K >> 6;

    const _Float16* aptr[2];
#pragma unroll
    for (int it = 0; it < 2; ++it) {
        int p = it * 512 + tid;
        int row = p >> 3;
        int g = (p & 7) ^ FKEY(row);
        aptr[it] = Xh + (size_t)(mB + row) * K + (g << 3);
    }
    char* as_base = (char*)As;

    const int brow = tid >> 1;
    const int bhc  = tid & 1;
    const unsigned char* bptr = W8 + (size_t)(nB + brow) * K + (bhc << 5);
    const int bfk = FKEY(brow);
    _Float16* brow_lds = Bs + (brow << 6);
    const int bg0 = bhc << 2;

    const int wm = (wid >> 2) << 6;
    const int wn = (wid & 3) << 6;
    const int fr = lane & 31;
    const int kh = lane >> 5;
    const int fkey = FKEY(fr);

    f32x16 acc[2][2] = {};

    for (int kt = 0; kt < kIters; ++kt) {
#pragma unroll
        for (int it = 0; it < 2; ++it) {
            gl_lds16(aptr[it], as_base + ((it * 512 + tid) << 4));
            aptr[it] += 64;
        }
        uint4 q0 = *(const uint4*)(bptr);
        uint4 q1 = *(const uint4*)(bptr + 16);
        bptr += 64;
        half8 d0 = dec8(q0.x, q0.y);
        half8 d1 = dec8(q0.z, q0.w);
        half8 d2 = dec8(q1.x, q1.y);
        half8 d3 = dec8(q1.z, q1.w);
        *(half8*)(brow_lds + (((bg0 + 0) ^ bfk) << 3)) = d0;
        *(half8*)(brow_lds + (((bg0 + 1) ^ bfk) << 3)) = d1;
        *(half8*)(brow_lds + (((bg0 + 2) ^ bfk) << 3)) = d2;
        *(half8*)(brow_lds + (((bg0 + 3) ^ bfk) << 3)) = d3;
        __syncthreads();

#pragma unroll
        for (int ks = 0; ks < 4; ++ks) {
            const int lc = (ks << 1) + kh;
            half8 a[2], bb[2];
#pragma unroll
            for (int i = 0; i < 2; ++i) {
                const int co = ((lc ^ fkey ^ (i << 2)) << 3);
                a[i]  = *(const half8*)(As + ((wm + (i << 5) + fr) << 6) + co);
                bb[i] = *(const half8*)(Bs + ((wn + (i << 5) + fr) << 6) + co);
            }
#pragma unroll
            for (int mi = 0; mi < 2; ++mi)
#pragma unroll
                for (int ni = 0; ni < 2; ++ni)
                    acc[mi][ni] = __builtin_amdgcn_mfma_f32_32x32x16_f16(
                        a[mi], bb[ni], acc[mi][ni], 0, 0, 0);
        }
        __syncthreads();
    }

#pragma unroll
    for (int ni = 0; ni < 2; ++ni) {
        int col = nB + wn + (ni << 5) + fr;
        float bv = dec_hf8((unsigned)bias_codes[col]);
#pragma unroll
        for (int mi = 0; mi < 2; ++mi) {
            int rbase = mB + wm + (mi << 5) + (kh << 2);
#pragma unroll
            for (int r = 0; r < 16; ++r) {
                int row = rbase + (r & 3) + ((r >> 2) << 3);
                C[(size_t)row * N + col] = acc[mi][ni][r] + bv;
            }
        }
    }
}

// ---------------- correctness parachute ----------------
__global__ void naive_kernel(const float* __restrict__ X, const int* __restrict__ Wc,
                             const int* __restrict__ Bc, float* __restrict__ C,
                             int M, int N, int K) {
    long long idx = (long long)blockIdx.x * 256 + threadIdx.x;
    if (idx >= (long long)M * N) return;
    int m = (int)(idx / N);
    int n = (int)(idx % N);
    float s = dec_hf8((unsigned)Bc[n]);
    const float* x = X + (size_t)m * K;
    const int* w = Wc + (size_t)n * K;
    for (int k = 0; k < K; ++k) s += x[k] * dec_hf8((unsigned)w[k]);
    C[idx] = s;
}

extern "C" void kernel_launch(void* const* d_in, const int* in_sizes, int n_in,
                              void* d_out, int out_size, void* d_ws, size_t ws_size,
                              hipStream_t stream) {
    const float* X  = (const float*)d_in[0];   // x: fp16 promoted to fp32 by harness
    const int*   Wc = (const int*)d_in[1];     // weight codes as int32
    const int*   Bc = (const int*)d_in[2];     // bias codes as int32
    float* C = (float*)d_out;

    long long wn = (long long)in_sizes[1];     // D_OUT * D_IN
    int N = in_sizes[2];                       // D_OUT
    int K = (int)(wn / N);                     // D_IN
    long long xn = (long long)in_sizes[0];
    int M = (int)(xn / K);                     // B*S

    size_t needXh = (size_t)xn * sizeof(_Float16);
    size_t needWh = (size_t)wn * sizeof(_Float16);
    size_t needW8 = (size_t)wn;

    bool ok8 = (M % 256 == 0) && (N % 256 == 0) && (K % 64 == 0) &&
               (wn % 16 == 0) && (xn % 8 == 0) &&
               (ws_size >= ((needXh + 15) & ~(size_t)15) + needWh + 16);
    bool okOld = (M % 128 == 0) && (N % 256 == 0) && (K % 64 == 0) &&
                 (wn % 16 == 0) && (xn % 8 == 0) &&
                 (ws_size >= needW8 + needXh + 16);

    if (ok8) {
        _Float16* Xh = (_Float16*)d_ws;
        _Float16* Wh = (_Float16*)((char*)d_ws + ((needXh + 15) & ~(size_t)15));
        cvt_x<<<dim3((unsigned)((xn / 8 + 255) / 256)), dim3(256), 0, stream>>>(X, Xh, xn / 8);
        decode_w<<<dim3((unsigned)((wn / 16 + 255) / 256)), dim3(256), 0, stream>>>(
            Wc, Wh, wn / 16);
        unsigned blocks = (unsigned)((M / 256) * (N / 256));
        hgemm_8ph<<<dim3(blocks), dim3(512), 0, stream>>>(Xh, Wh, Bc, C, M, N, K);
    } else if (okOld) {
        unsigned char* W8 = (unsigned char*)d_ws;
        _Float16* Xh = (_Float16*)((char*)d_ws + ((needW8 + 15) & ~(size_t)15));
        repack_codes<<<dim3((unsigned)((wn / 16 + 255) / 256)), dim3(256), 0, stream>>>(
            Wc, (unsigned*)W8, wn / 16);
        cvt_x<<<dim3((unsigned)((xn / 8 + 255) / 256)), dim3(256), 0, stream>>>(X, Xh, xn / 8);
        unsigned blocks = (unsigned)((M / 128) * (N / 256));
        hgemm_x2<<<dim3(blocks), dim3(512), 0, stream>>>(Xh, W8, Bc, C, M, N, K);
    } else {
        long long total = (long long)M * N;
        naive_kernel<<<dim3((unsigned)((total + 255) / 256)), dim3(256), 0, stream>>>(
            X, Wc, Bc, C, M, N, K);
    }
}